// Round 1
// baseline (6336.590 us; speedup 1.0000x reference)
//
#include <hip/hip_runtime.h>
#include <hip/hip_bf16.h>

#define DPAD 132  // 64-row LDS tile leading dim: 16B-aligned float4 stores, tolerable bank spread

// ---------------- scan helpers ----------------
__device__ __forceinline__ int waveScanIncl(int x) {
  int lane = threadIdx.x & 63;
  #pragma unroll
  for (int o = 1; o < 64; o <<= 1) {
    int y = __shfl_up(x, (unsigned)o, 64);
    if (lane >= o) x += y;
  }
  return x;
}

// 256-thread block; t3 = per-thread total of its 4 items.
// excl = exclusive prefix of this thread's first item, btot = block total.
__device__ __forceinline__ void blockScan(int t3, int* excl, int* btot) {
  __shared__ int wsum[4];
  int incl = waveScanIncl(t3);
  int wid = threadIdx.x >> 6, lane = threadIdx.x & 63;
  if (lane == 63) wsum[wid] = incl;
  __syncthreads();
  int woff = 0, tot = 0;
  #pragma unroll
  for (int w = 0; w < 4; w++) { int s = wsum[w]; tot += s; if (w < wid) woff += s; }
  *excl = woff + incl - t3;
  *btot = tot;
  __syncthreads();
}

// ---------------- setup kernels ----------------
__global__ void k_endpoints(const int* __restrict__ v_edge, const int* __restrict__ c_edge,
                            const int* __restrict__ p_edge, const int* __restrict__ n_edge,
                            int Eh, int nC, int nV,
                            int* __restrict__ pv, int* __restrict__ pc,
                            int* __restrict__ nv, int* __restrict__ nc,
                            int* __restrict__ hist) {
  int i = blockIdx.x * 256 + threadIdx.x;
  if (i >= 2 * Eh) return;
  int half = (i >= Eh) ? 1 : 0;
  int j = i - half * Eh;
  int e = (half ? n_edge : p_edge)[j];
  int v = v_edge[e], c = c_edge[e];
  if (half) { nv[j] = v; nc[j] = c; } else { pv[j] = v; pc[j] = c; }
  atomicAdd(&hist[half * nC + c], 1);
  atomicAdd(&hist[2 * nC + half * nV + v], 1);
}

__global__ void k_scanA(const int* __restrict__ hist, int nC, int nV,
                        int* __restrict__ off_pc, int* __restrict__ off_nc,
                        int* __restrict__ off_pv, int* __restrict__ off_nv,
                        int* __restrict__ bsums) {
  int BC = (nC + 1023) >> 10, BV = (nV + 1023) >> 10;
  int b = blockIdx.x;
  const int* in; int* off; int bin, n;
  if (b < BC)               { in = hist;                 off = off_pc; bin = b;               n = nC; }
  else if (b < 2*BC)        { in = hist + nC;            off = off_nc; bin = b - BC;          n = nC; }
  else if (b < 2*BC + BV)   { in = hist + 2*nC;          off = off_pv; bin = b - 2*BC;        n = nV; }
  else                      { in = hist + 2*nC + nV;     off = off_nv; bin = b - 2*BC - BV;   n = nV; }
  int base = (bin << 10) + (threadIdx.x << 2);
  int v[4];
  #pragma unroll
  for (int k = 0; k < 4; k++) v[k] = (base + k < n) ? in[base + k] : 0;
  int t0 = v[0], t1 = t0 + v[1], t2 = t1 + v[2], t3 = t2 + v[3];
  int excl, btot; blockScan(t3, &excl, &btot);
  int pre[4] = {excl, excl + t0, excl + t1, excl + t2};
  #pragma unroll
  for (int k = 0; k < 4; k++) if (base + k < n) off[base + k] = pre[k];
  if (threadIdx.x == 0) bsums[b] = btot;
}

__global__ void k_scanB(int nC, int nV,
                        int* __restrict__ off_pc, int* __restrict__ off_nc,
                        int* __restrict__ off_pv, int* __restrict__ off_nv,
                        int* __restrict__ bsums) {
  int BC = (nC + 1023) >> 10, BV = (nV + 1023) >> 10;
  int b = blockIdx.x;
  int segBase, nb, n; int* off;
  if (b == 0)      { segBase = 0;          nb = BC; off = off_pc; n = nC; }
  else if (b == 1) { segBase = BC;         nb = BC; off = off_nc; n = nC; }
  else if (b == 2) { segBase = 2*BC;       nb = BV; off = off_pv; n = nV; }
  else             { segBase = 2*BC + BV;  nb = BV; off = off_nv; n = nV; }
  int base = threadIdx.x << 2;
  int v[4];
  #pragma unroll
  for (int k = 0; k < 4; k++) v[k] = (base + k < nb) ? bsums[segBase + base + k] : 0;
  int t0 = v[0], t1 = t0 + v[1], t2 = t1 + v[2], t3 = t2 + v[3];
  int excl, btot; blockScan(t3, &excl, &btot);
  int pre[4] = {excl, excl + t0, excl + t1, excl + t2};
  #pragma unroll
  for (int k = 0; k < 4; k++) if (base + k < nb) bsums[segBase + base + k] = pre[k];
  if (threadIdx.x == 0) off[n] = btot;  // segment total == Eh
}

__global__ void k_scanC(int nC, int nV,
                        int* __restrict__ off_pc, int* __restrict__ off_nc,
                        int* __restrict__ off_pv, int* __restrict__ off_nv,
                        int* __restrict__ cur_pc, int* __restrict__ cur_nc,
                        int* __restrict__ cur_pv, int* __restrict__ cur_nv,
                        const int* __restrict__ bsums) {
  int BC = (nC + 1023) >> 10, BV = (nV + 1023) >> 10;
  int b = blockIdx.x;
  int* off; int* cur; int bin, n;
  if (b < BC)             { off = off_pc; cur = cur_pc; bin = b;             n = nC; }
  else if (b < 2*BC)      { off = off_nc; cur = cur_nc; bin = b - BC;        n = nC; }
  else if (b < 2*BC + BV) { off = off_pv; cur = cur_pv; bin = b - 2*BC;      n = nV; }
  else                    { off = off_nv; cur = cur_nv; bin = b - 2*BC - BV; n = nV; }
  int add = bsums[b];
  int base = (bin << 10) + (threadIdx.x << 2);
  #pragma unroll
  for (int k = 0; k < 4; k++) {
    int i = base + k;
    if (i < n) { int val = off[i] + add; off[i] = val; cur[i] = val; }
  }
}

__global__ void k_fill(int Eh, int nC, int nV,
                       const int* __restrict__ pv, const int* __restrict__ pc,
                       const int* __restrict__ nv, const int* __restrict__ nc,
                       const int* __restrict__ hist,
                       int* __restrict__ cur_pc, int* __restrict__ cur_nc,
                       int* __restrict__ cur_pv, int* __restrict__ cur_nv,
                       int* __restrict__ sPC, float* __restrict__ wPC,
                       int* __restrict__ sNC, float* __restrict__ wNC,
                       int* __restrict__ sPV, float* __restrict__ wPV,
                       int* __restrict__ sNV, float* __restrict__ wNV) {
  int i = blockIdx.x * 256 + threadIdx.x;
  if (i >= 2 * Eh) return;
  int half = (i >= Eh) ? 1 : 0;
  int j = i - half * Eh;
  int v = half ? nv[j] : pv[j];
  int c = half ? nc[j] : pc[j];
  int dc = hist[half * nC + c];
  int dv = hist[2 * nC + half * nV + v];
  float inv = rsqrtf((float)max(dc, 1) * (float)max(dv, 1));
  int* curc = half ? cur_nc : cur_pc;
  int* curv = half ? cur_nv : cur_pv;
  int p1 = atomicAdd(&curc[c], 1);
  if (half) { sNC[p1] = v; wNC[p1] = inv; } else { sPC[p1] = v; wPC[p1] = inv; }
  int p2 = atomicAdd(&curv[v], 1);
  if (half) { sNV[p2] = c; wNV[p2] = inv; } else { sPV[p2] = c; wPV[p2] = inv; }
}

// ---------------- per-node 2-layer MLP (128->128 relu ->128), bf16 output ----------------
// block = 128 threads = 2 waves; 64 rows/block; wave w covers output cols [w*64, w*64+64).
// Weight loads use wave-uniform addresses -> expect SMEM (s_load) scalarization.
__global__ __launch_bounds__(128) void k_mlp2(const float* __restrict__ X, int nrows,
                                              const float* __restrict__ W, const float* __restrict__ B,
                                              __hip_bfloat16* __restrict__ out) {
  __shared__ float xs[64 * DPAD];
  int rowBase = blockIdx.x << 6;
  int rows = min(64, nrows - rowBase);
  int tid = threadIdx.x;
  const float4* Xv = (const float4*)(X + (size_t)rowBase * 128);
  int n4 = rows << 5;
  for (int i = tid; i < n4; i += 128) {
    float4 val = Xv[i];
    int r = i >> 5, k4 = (i & 31) << 2;
    *(float4*)&xs[r * DPAD + k4] = val;
  }
  __syncthreads();
  int lane = tid & 63;
  int j0 = __builtin_amdgcn_readfirstlane((tid >> 6) << 6);
  const float* xrow = &xs[lane * DPAD];
  float acc[64];
  #pragma unroll
  for (int jj = 0; jj < 64; jj++) acc[jj] = B[j0 + jj];
  for (int k = 0; k < 128; k++) {
    float xv = xrow[k];
    const float* wr = &W[k * 128 + j0];
    #pragma unroll
    for (int jj = 0; jj < 64; jj++) acc[jj] = fmaf(wr[jj], xv, acc[jj]);
  }
  __syncthreads();
  #pragma unroll
  for (int jj = 0; jj < 64; jj += 4) {
    float4 h = { fmaxf(acc[jj], 0.f), fmaxf(acc[jj+1], 0.f), fmaxf(acc[jj+2], 0.f), fmaxf(acc[jj+3], 0.f) };
    *(float4*)&xs[lane * DPAD + j0 + jj] = h;
  }
  __syncthreads();
  #pragma unroll
  for (int jj = 0; jj < 64; jj++) acc[jj] = B[128 + j0 + jj];
  const float* W1 = W + 16384;
  for (int k = 0; k < 128; k++) {
    float xv = xrow[k];
    const float* wr = &W1[k * 128 + j0];
    #pragma unroll
    for (int jj = 0; jj < 64; jj++) acc[jj] = fmaf(wr[jj], xv, acc[jj]);
  }
  if (lane < rows) {
    __hip_bfloat16* op = out + (size_t)(rowBase + lane) * 128 + j0;
    #pragma unroll
    for (int jj = 0; jj < 64; jj += 2) {
      __hip_bfloat162 h2;
      h2.x = __float2bfloat16(acc[jj]);
      h2.y = __float2bfloat16(acc[jj + 1]);
      *(__hip_bfloat162*)(op + jj) = h2;
    }
  }
}

// ---------------- fused CSR-aggregate + concat(384) GEMM update ----------------
// out = [X, aggP(M1), aggN(M2)] @ UW + UB ; same 64-rows/2-waves mapping, 3 K-chunks.
__global__ __launch_bounds__(128) void k_update(const float* __restrict__ X, int nrows,
                                                const __hip_bfloat16* __restrict__ M1,
                                                const __hip_bfloat16* __restrict__ M2,
                                                const int* __restrict__ offP, const int* __restrict__ srcP, const float* __restrict__ wP,
                                                const int* __restrict__ offN, const int* __restrict__ srcN, const float* __restrict__ wN,
                                                const float* __restrict__ UW, const float* __restrict__ UB,
                                                float* __restrict__ out) {
  __shared__ float xs[64 * DPAD];
  int rowBase = blockIdx.x << 6;
  int rows = min(64, nrows - rowBase);
  int tid = threadIdx.x;
  int lane = tid & 63;
  int j0 = __builtin_amdgcn_readfirstlane((tid >> 6) << 6);
  const float* xrow = &xs[lane * DPAD];
  float acc[64];
  #pragma unroll
  for (int jj = 0; jj < 64; jj++) acc[jj] = 0.f;

  // chunk 0: previous embedding tile
  {
    const float4* Xv = (const float4*)(X + (size_t)rowBase * 128);
    int n4 = rows << 5;
    for (int i = tid; i < n4; i += 128) {
      float4 val = Xv[i];
      int r = i >> 5, k4 = (i & 31) << 2;
      *(float4*)&xs[r * DPAD + k4] = val;
    }
  }
  __syncthreads();
  {
    const float* Wc = UW + j0;
    for (int k = 0; k < 128; k++) {
      float xv = xrow[k];
      const float* wr = Wc + k * 128;
      #pragma unroll
      for (int jj = 0; jj < 64; jj++) acc[jj] = fmaf(wr[jj], xv, acc[jj]);
    }
  }
  __syncthreads();

  // chunk 1: positive-polarity aggregation from M1 (thread = feature column)
  for (int r = 0; r < rows; r++) {
    int e0 = offP[rowBase + r], e1 = offP[rowBase + r + 1];
    float a = 0.f;
    for (int e = e0; e < e1; e++)
      a += wP[e] * __bfloat162float(M1[(size_t)srcP[e] * 128 + tid]);
    xs[r * DPAD + tid] = a;
  }
  __syncthreads();
  {
    const float* Wc = UW + 128 * 128 + j0;
    for (int k = 0; k < 128; k++) {
      float xv = xrow[k];
      const float* wr = Wc + k * 128;
      #pragma unroll
      for (int jj = 0; jj < 64; jj++) acc[jj] = fmaf(wr[jj], xv, acc[jj]);
    }
  }
  __syncthreads();

  // chunk 2: negative-polarity aggregation from M2
  for (int r = 0; r < rows; r++) {
    int e0 = offN[rowBase + r], e1 = offN[rowBase + r + 1];
    float a = 0.f;
    for (int e = e0; e < e1; e++)
      a += wN[e] * __bfloat162float(M2[(size_t)srcN[e] * 128 + tid]);
    xs[r * DPAD + tid] = a;
  }
  __syncthreads();
  {
    const float* Wc = UW + 2 * 128 * 128 + j0;
    for (int k = 0; k < 128; k++) {
      float xv = xrow[k];
      const float* wr = Wc + k * 128;
      #pragma unroll
      for (int jj = 0; jj < 64; jj++) acc[jj] = fmaf(wr[jj], xv, acc[jj]);
    }
  }

  if (lane < rows) {
    float* op = out + (size_t)(rowBase + lane) * 128 + j0;
    #pragma unroll
    for (int jj = 0; jj < 64; jj += 4) {
      float4 o = { acc[jj] + UB[j0 + jj], acc[jj+1] + UB[j0 + jj + 1],
                   acc[jj+2] + UB[j0 + jj + 2], acc[jj+3] + UB[j0 + jj + 3] };
      *(float4*)(op + jj) = o;
    }
  }
}

// ---------------- launch ----------------
extern "C" void kernel_launch(void* const* d_in, const int* in_sizes, int n_in,
                              void* d_out, int out_size, void* d_ws, size_t ws_size,
                              hipStream_t stream) {
  const int* v_edge = (const int*)d_in[2];
  const int* c_edge = (const int*)d_in[3];
  const int* p_edge = (const int*)d_in[4];
  const int* n_edge = (const int*)d_in[5];
  const float* v_emb0 = (const float*)d_in[6];
  const float* c_emb0 = (const float*)d_in[7];
  const float* Wpv2c = (const float*)d_in[8];  const float* Bpv2c = (const float*)d_in[9];
  const float* Wnv2c = (const float*)d_in[10]; const float* Bnv2c = (const float*)d_in[11];
  const float* Wpc2v = (const float*)d_in[12]; const float* Bpc2v = (const float*)d_in[13];
  const float* Wnc2v = (const float*)d_in[14]; const float* Bnc2v = (const float*)d_in[15];
  const float* cuW = (const float*)d_in[16];   const float* cuB = (const float*)d_in[17];
  const float* vuW = (const float*)d_in[18];   const float* vuB = (const float*)d_in[19];

  const int V = in_sizes[6] / 128;
  const int C = in_sizes[7] / 128;
  const int Eh = in_sizes[4];

  char* p = (char*)d_ws;
  auto alloc = [&](size_t bytes) { char* r = p; p += (bytes + 255) & ~(size_t)255; return r; };
  int* off_pc = (int*)alloc((size_t)(C + 1) * 4); int* cur_pc = (int*)alloc((size_t)(C + 1) * 4);
  int* off_nc = (int*)alloc((size_t)(C + 1) * 4); int* cur_nc = (int*)alloc((size_t)(C + 1) * 4);
  int* off_pv = (int*)alloc((size_t)(V + 1) * 4); int* cur_pv = (int*)alloc((size_t)(V + 1) * 4);
  int* off_nv = (int*)alloc((size_t)(V + 1) * 4); int* cur_nv = (int*)alloc((size_t)(V + 1) * 4);
  int* hist = (int*)alloc((size_t)(2 * C + 2 * V) * 4);
  int* pv = (int*)alloc((size_t)Eh * 4); int* pc = (int*)alloc((size_t)Eh * 4);
  int* nv = (int*)alloc((size_t)Eh * 4); int* nc = (int*)alloc((size_t)Eh * 4);
  int* sPC = (int*)alloc((size_t)Eh * 4); float* wPC = (float*)alloc((size_t)Eh * 4);
  int* sNC = (int*)alloc((size_t)Eh * 4); float* wNC = (float*)alloc((size_t)Eh * 4);
  int* sPV = (int*)alloc((size_t)Eh * 4); float* wPV = (float*)alloc((size_t)Eh * 4);
  int* sNV = (int*)alloc((size_t)Eh * 4); float* wNV = (float*)alloc((size_t)Eh * 4);
  int* bsums = (int*)alloc(4096);
  __hip_bfloat16* M1 = (__hip_bfloat16*)alloc((size_t)C * 128 * 2);
  __hip_bfloat16* M2 = (__hip_bfloat16*)alloc((size_t)C * 128 * 2);
  if ((size_t)(p - (char*)d_ws) > ws_size) return;  // ws too small: fail loudly via absmax

  float* vout = (float*)d_out;
  float* cout = vout + (size_t)4 * V * 128;

  hipMemsetAsync(hist, 0, (size_t)(2 * C + 2 * V) * 4, stream);
  int eb = (2 * Eh + 255) / 256;
  k_endpoints<<<eb, 256, 0, stream>>>(v_edge, c_edge, p_edge, n_edge, Eh, C, V, pv, pc, nv, nc, hist);
  int BC = (C + 1023) >> 10, BV = (V + 1023) >> 10;
  k_scanA<<<2 * BC + 2 * BV, 256, 0, stream>>>(hist, C, V, off_pc, off_nc, off_pv, off_nv, bsums);
  k_scanB<<<4, 256, 0, stream>>>(C, V, off_pc, off_nc, off_pv, off_nv, bsums);
  k_scanC<<<2 * BC + 2 * BV, 256, 0, stream>>>(C, V, off_pc, off_nc, off_pv, off_nv,
                                               cur_pc, cur_nc, cur_pv, cur_nv, bsums);
  k_fill<<<eb, 256, 0, stream>>>(Eh, C, V, pv, pc, nv, nc, hist,
                                 cur_pc, cur_nc, cur_pv, cur_nv,
                                 sPC, wPC, sNC, wNC, sPV, wPV, sNV, wNV);
  hipMemcpyAsync(vout, v_emb0, (size_t)V * 128 * 4, hipMemcpyDeviceToDevice, stream);
  hipMemcpyAsync(cout, c_emb0, (size_t)C * 128 * 4, hipMemcpyDeviceToDevice, stream);

  int vb = (V + 63) / 64, cb = (C + 63) / 64;
  for (int t = 1; t <= 3; t++) {
    const float* vprev = vout + (size_t)(t - 1) * V * 128;
    const float* cprev = cout + (size_t)(t - 1) * C * 128;
    float* vnext = vout + (size_t)t * V * 128;
    float* cnext = cout + (size_t)t * C * 128;
    k_mlp2<<<vb, 128, 0, stream>>>(vprev, V, Wpv2c, Bpv2c, M1);
    k_mlp2<<<vb, 128, 0, stream>>>(vprev, V, Wnv2c, Bnv2c, M2);
    k_update<<<cb, 128, 0, stream>>>(cprev, C, M1, M2, off_pc, sPC, wPC, off_nc, sNC, wNC, cuW, cuB, cnext);
    k_mlp2<<<cb, 128, 0, stream>>>(cprev, C, Wpc2v, Bpc2v, M1);
    k_mlp2<<<cb, 128, 0, stream>>>(cprev, C, Wnc2v, Bnc2v, M2);
    k_update<<<vb, 128, 0, stream>>>(vprev, V, M1, M2, off_pv, sPV, wPV, off_nv, sNV, wNV, vuW, vuB, vnext);
  }
}

// Round 2
// 1694.596 us; speedup vs baseline: 3.7393x; 3.7393x over previous
//
#include <hip/hip_runtime.h>

#define KP 136  // padded K stride (bf16 elems): 16B-aligned rows, 2-way LDS bank aliasing (free)

typedef __attribute__((ext_vector_type(8))) short short8;
typedef __attribute__((ext_vector_type(4))) float floatx4;

__device__ __forceinline__ unsigned short f2b(float f) {
  union { float f; unsigned int u; } x; x.f = f;
  return (unsigned short)((x.u + 0x7FFFu + ((x.u >> 16) & 1u)) >> 16);
}
__device__ __forceinline__ float b2f(unsigned short b) {
  union { unsigned int u; float f; } x; x.u = ((unsigned int)b) << 16;
  return x.f;
}

// ---------------- scan helpers ----------------
__device__ __forceinline__ int waveScanIncl(int x) {
  int lane = threadIdx.x & 63;
  #pragma unroll
  for (int o = 1; o < 64; o <<= 1) {
    int y = __shfl_up(x, (unsigned)o, 64);
    if (lane >= o) x += y;
  }
  return x;
}

__device__ __forceinline__ void blockScan(int t3, int* excl, int* btot) {
  __shared__ int wsum[4];
  int incl = waveScanIncl(t3);
  int wid = threadIdx.x >> 6, lane = threadIdx.x & 63;
  if (lane == 63) wsum[wid] = incl;
  __syncthreads();
  int woff = 0, tot = 0;
  #pragma unroll
  for (int w = 0; w < 4; w++) { int s = wsum[w]; tot += s; if (w < wid) woff += s; }
  *excl = woff + incl - t3;
  *btot = tot;
  __syncthreads();
}

// ---------------- setup kernels ----------------
__global__ void k_endpoints(const int* __restrict__ v_edge, const int* __restrict__ c_edge,
                            const int* __restrict__ p_edge, const int* __restrict__ n_edge,
                            int Eh, int nC, int nV,
                            int* __restrict__ pv, int* __restrict__ pc,
                            int* __restrict__ nv, int* __restrict__ nc,
                            int* __restrict__ hist) {
  int i = blockIdx.x * 256 + threadIdx.x;
  if (i >= 2 * Eh) return;
  int half = (i >= Eh) ? 1 : 0;
  int j = i - half * Eh;
  int e = (half ? n_edge : p_edge)[j];
  int v = v_edge[e], c = c_edge[e];
  if (half) { nv[j] = v; nc[j] = c; } else { pv[j] = v; pc[j] = c; }
  atomicAdd(&hist[half * nC + c], 1);
  atomicAdd(&hist[2 * nC + half * nV + v], 1);
}

__global__ void k_scanA(const int* __restrict__ hist, int nC, int nV,
                        int* __restrict__ off_pc, int* __restrict__ off_nc,
                        int* __restrict__ off_pv, int* __restrict__ off_nv,
                        int* __restrict__ bsums) {
  int BC = (nC + 1023) >> 10, BV = (nV + 1023) >> 10;
  int b = blockIdx.x;
  const int* in; int* off; int bin, n;
  if (b < BC)               { in = hist;                 off = off_pc; bin = b;               n = nC; }
  else if (b < 2*BC)        { in = hist + nC;            off = off_nc; bin = b - BC;          n = nC; }
  else if (b < 2*BC + BV)   { in = hist + 2*nC;          off = off_pv; bin = b - 2*BC;        n = nV; }
  else                      { in = hist + 2*nC + nV;     off = off_nv; bin = b - 2*BC - BV;   n = nV; }
  int base = (bin << 10) + (threadIdx.x << 2);
  int v[4];
  #pragma unroll
  for (int k = 0; k < 4; k++) v[k] = (base + k < n) ? in[base + k] : 0;
  int t0 = v[0], t1 = t0 + v[1], t2 = t1 + v[2], t3 = t2 + v[3];
  int excl, btot; blockScan(t3, &excl, &btot);
  int pre[4] = {excl, excl + t0, excl + t1, excl + t2};
  #pragma unroll
  for (int k = 0; k < 4; k++) if (base + k < n) off[base + k] = pre[k];
  if (threadIdx.x == 0) bsums[b] = btot;
}

__global__ void k_scanB(int nC, int nV,
                        int* __restrict__ off_pc, int* __restrict__ off_nc,
                        int* __restrict__ off_pv, int* __restrict__ off_nv,
                        int* __restrict__ bsums) {
  int BC = (nC + 1023) >> 10, BV = (nV + 1023) >> 10;
  int b = blockIdx.x;
  int segBase, nb, n; int* off;
  if (b == 0)      { segBase = 0;          nb = BC; off = off_pc; n = nC; }
  else if (b == 1) { segBase = BC;         nb = BC; off = off_nc; n = nC; }
  else if (b == 2) { segBase = 2*BC;       nb = BV; off = off_pv; n = nV; }
  else             { segBase = 2*BC + BV;  nb = BV; off = off_nv; n = nV; }
  int base = threadIdx.x << 2;
  int v[4];
  #pragma unroll
  for (int k = 0; k < 4; k++) v[k] = (base + k < nb) ? bsums[segBase + base + k] : 0;
  int t0 = v[0], t1 = t0 + v[1], t2 = t1 + v[2], t3 = t2 + v[3];
  int excl, btot; blockScan(t3, &excl, &btot);
  int pre[4] = {excl, excl + t0, excl + t1, excl + t2};
  #pragma unroll
  for (int k = 0; k < 4; k++) if (base + k < nb) bsums[segBase + base + k] = pre[k];
  if (threadIdx.x == 0) off[n] = btot;
}

__global__ void k_scanC(int nC, int nV,
                        int* __restrict__ off_pc, int* __restrict__ off_nc,
                        int* __restrict__ off_pv, int* __restrict__ off_nv,
                        int* __restrict__ cur_pc, int* __restrict__ cur_nc,
                        int* __restrict__ cur_pv, int* __restrict__ cur_nv,
                        const int* __restrict__ bsums) {
  int BC = (nC + 1023) >> 10, BV = (nV + 1023) >> 10;
  int b = blockIdx.x;
  int* off; int* cur; int bin, n;
  if (b < BC)             { off = off_pc; cur = cur_pc; bin = b;             n = nC; }
  else if (b < 2*BC)      { off = off_nc; cur = cur_nc; bin = b - BC;        n = nC; }
  else if (b < 2*BC + BV) { off = off_pv; cur = cur_pv; bin = b - 2*BC;      n = nV; }
  else                    { off = off_nv; cur = cur_nv; bin = b - 2*BC - BV; n = nV; }
  int add = bsums[b];
  int base = (bin << 10) + (threadIdx.x << 2);
  #pragma unroll
  for (int k = 0; k < 4; k++) {
    int i = base + k;
    if (i < n) { int val = off[i] + add; off[i] = val; cur[i] = val; }
  }
}

__global__ void k_fill(int Eh, int nC, int nV,
                       const int* __restrict__ pv, const int* __restrict__ pc,
                       const int* __restrict__ nv, const int* __restrict__ nc,
                       const int* __restrict__ hist,
                       int* __restrict__ cur_pc, int* __restrict__ cur_nc,
                       int* __restrict__ cur_pv, int* __restrict__ cur_nv,
                       int* __restrict__ sPC, float* __restrict__ wPC,
                       int* __restrict__ sNC, float* __restrict__ wNC,
                       int* __restrict__ sPV, float* __restrict__ wPV,
                       int* __restrict__ sNV, float* __restrict__ wNV) {
  int i = blockIdx.x * 256 + threadIdx.x;
  if (i >= 2 * Eh) return;
  int half = (i >= Eh) ? 1 : 0;
  int j = i - half * Eh;
  int v = half ? nv[j] : pv[j];
  int c = half ? nc[j] : pc[j];
  int dc = hist[half * nC + c];
  int dv = hist[2 * nC + half * nV + v];
  float inv = rsqrtf((float)max(dc, 1) * (float)max(dv, 1));
  int* curc = half ? cur_nc : cur_pc;
  int* curv = half ? cur_nv : cur_pv;
  int p1 = atomicAdd(&curc[c], 1);
  if (half) { sNC[p1] = v; wNC[p1] = inv; } else { sPC[p1] = v; wPC[p1] = inv; }
  int p2 = atomicAdd(&curv[v], 1);
  if (half) { sNV[p2] = c; wNV[p2] = inv; } else { sPV[p2] = c; wPV[p2] = inv; }
}

// ---------------- weight transpose + bf16 convert: W[l][k][n] -> WT[l][n][k] ----------------
__global__ void k_wt(const float* __restrict__ W, int L, int K, int N,
                     unsigned short* __restrict__ out) {
  int idx = blockIdx.x * 256 + threadIdx.x;
  int tot = L * K * N;
  if (idx >= tot) return;
  int l = idx / (K * N), rem = idx - l * K * N;
  int n = rem / K, k = rem - n * K;
  out[idx] = f2b(W[l * K * N + k * N + n]);
}

// ---------------- fused dual-polarity 2-layer MLP, bf16 MFMA ----------------
// 256 thr = 4 waves; 64-row tile; wave w owns rows [w*16, w*16+16), all 128 cols (8 tiles).
// X A-frags cached in regs so the 17 KB A-buffer is reused for H. LDS = 52 KB -> 3 blocks/CU.
__global__ __launch_bounds__(256) void k_mlp_pair(
    const float* __restrict__ X, int nrows,
    const unsigned short* __restrict__ WTP, const float* __restrict__ BP,
    const unsigned short* __restrict__ WTN, const float* __restrict__ BN,
    unsigned short* __restrict__ M1, unsigned short* __restrict__ M2) {
  __shared__ unsigned short As[64 * KP];
  __shared__ unsigned short Ws[128 * KP];
  int tid = threadIdx.x;
  int rowBase = blockIdx.x << 6;
  int rows = min(64, nrows - rowBase);
  int lane = tid & 63, m = lane & 15, q = lane >> 4;
  int wrow = (tid >> 6) << 4;

  // stage X -> As (bf16, A-layout row-major [row][k])
  for (int c = tid; c < 2048; c += 256) {
    int r = c >> 5, off = (c & 31) << 2;
    float4 v = make_float4(0.f, 0.f, 0.f, 0.f);
    if (r < rows) v = *(const float4*)(X + (size_t)(rowBase + r) * 128 + off);
    unsigned short o[4] = {f2b(v.x), f2b(v.y), f2b(v.z), f2b(v.w)};
    *(unsigned long long*)&As[r * KP + off] = *(const unsigned long long*)o;
  }
  __syncthreads();
  short8 aX[4];
  #pragma unroll
  for (int k4 = 0; k4 < 4; k4++)
    aX[k4] = *(const short8*)&As[(wrow + m) * KP + k4 * 32 + q * 8];

  #pragma unroll 1
  for (int pol = 0; pol < 2; pol++) {
    const unsigned short* WT = pol ? WTN : WTP;
    const float* B = pol ? BN : BP;
    unsigned short* Mo = pol ? M2 : M1;

    // stage W0^T [n][k]
    for (int c = tid; c < 2048; c += 256) {
      int n = c >> 4, off = (c & 15) << 3;
      *(float4*)&Ws[n * KP + off] = *(const float4*)(WT + n * 128 + off);
    }
    __syncthreads();
    floatx4 acc[8];
    #pragma unroll
    for (int nt = 0; nt < 8; nt++) acc[nt] = (floatx4){0.f, 0.f, 0.f, 0.f};
    #pragma unroll
    for (int nt = 0; nt < 8; nt++) {
      #pragma unroll
      for (int k4 = 0; k4 < 4; k4++) {
        short8 b = *(const short8*)&Ws[(nt * 16 + m) * KP + k4 * 32 + q * 8];
        acc[nt] = __builtin_amdgcn_mfma_f32_16x16x32_bf16(aX[k4], b, acc[nt], 0, 0, 0);
      }
    }
    __syncthreads();
    // H = relu(acc + b0) -> As (A-layout); C/D map: col=lane&15, row=quad*4+reg
    #pragma unroll
    for (int nt = 0; nt < 8; nt++) {
      float bb = B[nt * 16 + m];
      #pragma unroll
      for (int reg = 0; reg < 4; reg++) {
        float h = fmaxf(acc[nt][reg] + bb, 0.f);
        As[(wrow + q * 4 + reg) * KP + nt * 16 + m] = f2b(h);
      }
    }
    // stage W1^T
    for (int c = tid; c < 2048; c += 256) {
      int n = c >> 4, off = (c & 15) << 3;
      *(float4*)&Ws[n * KP + off] = *(const float4*)(WT + 16384 + n * 128 + off);
    }
    __syncthreads();
    #pragma unroll
    for (int nt = 0; nt < 8; nt++) acc[nt] = (floatx4){0.f, 0.f, 0.f, 0.f};
    short8 aH[4];
    #pragma unroll
    for (int k4 = 0; k4 < 4; k4++)
      aH[k4] = *(const short8*)&As[(wrow + m) * KP + k4 * 32 + q * 8];
    #pragma unroll
    for (int nt = 0; nt < 8; nt++) {
      #pragma unroll
      for (int k4 = 0; k4 < 4; k4++) {
        short8 b = *(const short8*)&Ws[(nt * 16 + m) * KP + k4 * 32 + q * 8];
        acc[nt] = __builtin_amdgcn_mfma_f32_16x16x32_bf16(aH[k4], b, acc[nt], 0, 0, 0);
      }
    }
    __syncthreads();
    // D = acc + b1 -> As row-major bf16, then vectorized copy to global
    #pragma unroll
    for (int nt = 0; nt < 8; nt++) {
      float bb = B[128 + nt * 16 + m];
      #pragma unroll
      for (int reg = 0; reg < 4; reg++)
        As[(wrow + q * 4 + reg) * KP + nt * 16 + m] = f2b(acc[nt][reg] + bb);
    }
    __syncthreads();
    for (int c = tid; c < 1024; c += 256) {
      int r = c >> 4, off = (c & 15) << 3;
      if (r < rows)
        *(float4*)(Mo + (size_t)(rowBase + r) * 128 + off) = *(const float4*)&As[r * KP + off];
    }
    __syncthreads();
  }
}

// ---------------- fused CSR-aggregate + concat(384) GEMM update, bf16 MFMA ----------------
// K processed in 3 chunks of 128 (prev-emb, agg-P, agg-N); acc persists across chunks.
__global__ __launch_bounds__(256) void k_update_mfma(
    const float* __restrict__ X, int nrows,
    const unsigned short* __restrict__ M1, const unsigned short* __restrict__ M2,
    const int* __restrict__ offP, const int* __restrict__ srcP, const float* __restrict__ wP,
    const int* __restrict__ offN, const int* __restrict__ srcN, const float* __restrict__ wN,
    const unsigned short* __restrict__ UWT,  // [128 n][384 k] bf16
    const float* __restrict__ UB, float* __restrict__ out) {
  __shared__ unsigned short Ach[64 * KP];
  __shared__ unsigned short Ws[128 * KP];  // reused as fp32 out-staging [64][132] at the end
  int tid = threadIdx.x;
  int rowBase = blockIdx.x << 6;
  int rows = min(64, nrows - rowBase);
  int lane = tid & 63, m = lane & 15, q = lane >> 4;
  int wrow = (tid >> 6) << 4;
  floatx4 acc[8];
  #pragma unroll
  for (int nt = 0; nt < 8; nt++) acc[nt] = (floatx4){0.f, 0.f, 0.f, 0.f};

  #pragma unroll 1
  for (int ch = 0; ch < 3; ch++) {
    if (ch == 0) {
      for (int c = tid; c < 2048; c += 256) {
        int r = c >> 5, off = (c & 31) << 2;
        float4 v = make_float4(0.f, 0.f, 0.f, 0.f);
        if (r < rows) v = *(const float4*)(X + (size_t)(rowBase + r) * 128 + off);
        unsigned short o[4] = {f2b(v.x), f2b(v.y), f2b(v.z), f2b(v.w)};
        *(unsigned long long*)&Ach[r * KP + off] = *(const unsigned long long*)o;
      }
    } else {
      // row-per-quarter-wave CSR aggregation: thread = (row r, col quarter qt)
      const unsigned short* M = (ch == 1) ? M1 : M2;
      const int* off = (ch == 1) ? offP : offN;
      const int* src = (ch == 1) ? srcP : srcN;
      const float* wg = (ch == 1) ? wP : wN;
      int r = tid >> 2, qt = tid & 3;
      float a[32];
      #pragma unroll
      for (int i = 0; i < 32; i++) a[i] = 0.f;
      if (r < rows) {
        int e0 = off[rowBase + r], e1 = off[rowBase + r + 1];
        for (int e = e0; e < e1; e++) {
          int s = src[e]; float w = wg[e];
          const unsigned short* mp = M + (size_t)s * 128 + qt * 32;
          #pragma unroll
          for (int i = 0; i < 32; i += 8) {
            short8 v = *(const short8*)(mp + i);
            #pragma unroll
            for (int j = 0; j < 8; j++)
              a[i + j] = fmaf(w, b2f((unsigned short)v[j]), a[i + j]);
          }
        }
      }
      #pragma unroll
      for (int i = 0; i < 32; i += 8) {
        unsigned short o[8];
        #pragma unroll
        for (int j = 0; j < 8; j++) o[j] = f2b(a[i + j]);
        *(short8*)&Ach[r * KP + qt * 32 + i] = *(const short8*)o;
      }
    }
    // stage W chunk ch: UWT[n][ch*128 + k]
    for (int c = tid; c < 2048; c += 256) {
      int n = c >> 4, off2 = (c & 15) << 3;
      *(float4*)&Ws[n * KP + off2] = *(const float4*)(UWT + n * 384 + ch * 128 + off2);
    }
    __syncthreads();
    short8 aF[4];
    #pragma unroll
    for (int k4 = 0; k4 < 4; k4++)
      aF[k4] = *(const short8*)&Ach[(wrow + m) * KP + k4 * 32 + q * 8];
    #pragma unroll
    for (int nt = 0; nt < 8; nt++) {
      #pragma unroll
      for (int k4 = 0; k4 < 4; k4++) {
        short8 b = *(const short8*)&Ws[(nt * 16 + m) * KP + k4 * 32 + q * 8];
        acc[nt] = __builtin_amdgcn_mfma_f32_16x16x32_bf16(aF[k4], b, acc[nt], 0, 0, 0);
      }
    }
    __syncthreads();
  }
  // epilogue: D + bias -> fp32 LDS staging -> vectorized global store
  float* Os = (float*)Ws;
  #pragma unroll
  for (int nt = 0; nt < 8; nt++) {
    float bb = UB[nt * 16 + m];
    #pragma unroll
    for (int reg = 0; reg < 4; reg++)
      Os[(wrow + q * 4 + reg) * 132 + nt * 16 + m] = acc[nt][reg] + bb;
  }
  __syncthreads();
  for (int c = tid; c < 2048; c += 256) {
    int r = c >> 5, off2 = (c & 31) << 2;
    if (r < rows)
      *(float4*)(out + (size_t)(rowBase + r) * 128 + off2) = *(const float4*)&Os[r * 132 + off2];
  }
}

// ---------------- launch ----------------
extern "C" void kernel_launch(void* const* d_in, const int* in_sizes, int n_in,
                              void* d_out, int out_size, void* d_ws, size_t ws_size,
                              hipStream_t stream) {
  const int* v_edge = (const int*)d_in[2];
  const int* c_edge = (const int*)d_in[3];
  const int* p_edge = (const int*)d_in[4];
  const int* n_edge = (const int*)d_in[5];
  const float* v_emb0 = (const float*)d_in[6];
  const float* c_emb0 = (const float*)d_in[7];
  const float* Wpv2c = (const float*)d_in[8];  const float* Bpv2c = (const float*)d_in[9];
  const float* Wnv2c = (const float*)d_in[10]; const float* Bnv2c = (const float*)d_in[11];
  const float* Wpc2v = (const float*)d_in[12]; const float* Bpc2v = (const float*)d_in[13];
  const float* Wnc2v = (const float*)d_in[14]; const float* Bnc2v = (const float*)d_in[15];
  const float* cuW = (const float*)d_in[16];   const float* cuB = (const float*)d_in[17];
  const float* vuW = (const float*)d_in[18];   const float* vuB = (const float*)d_in[19];

  const int V = in_sizes[6] / 128;
  const int C = in_sizes[7] / 128;
  const int Eh = in_sizes[4];

  char* p = (char*)d_ws;
  auto alloc = [&](size_t bytes) { char* r = p; p += (bytes + 255) & ~(size_t)255; return r; };
  int* off_pc = (int*)alloc((size_t)(C + 1) * 4); int* cur_pc = (int*)alloc((size_t)(C + 1) * 4);
  int* off_nc = (int*)alloc((size_t)(C + 1) * 4); int* cur_nc = (int*)alloc((size_t)(C + 1) * 4);
  int* off_pv = (int*)alloc((size_t)(V + 1) * 4); int* cur_pv = (int*)alloc((size_t)(V + 1) * 4);
  int* off_nv = (int*)alloc((size_t)(V + 1) * 4); int* cur_nv = (int*)alloc((size_t)(V + 1) * 4);
  int* hist = (int*)alloc((size_t)(2 * C + 2 * V) * 4);
  int* pv = (int*)alloc((size_t)Eh * 4); int* pc = (int*)alloc((size_t)Eh * 4);
  int* nv = (int*)alloc((size_t)Eh * 4); int* nc = (int*)alloc((size_t)Eh * 4);
  int* sPC = (int*)alloc((size_t)Eh * 4); float* wPC = (float*)alloc((size_t)Eh * 4);
  int* sNC = (int*)alloc((size_t)Eh * 4); float* wNC = (float*)alloc((size_t)Eh * 4);
  int* sPV = (int*)alloc((size_t)Eh * 4); float* wPV = (float*)alloc((size_t)Eh * 4);
  int* sNV = (int*)alloc((size_t)Eh * 4); float* wNV = (float*)alloc((size_t)Eh * 4);
  int* bsums = (int*)alloc(4096);
  unsigned short* M1 = (unsigned short*)alloc((size_t)C * 128 * 2);
  unsigned short* M2 = (unsigned short*)alloc((size_t)C * 128 * 2);
  unsigned short* WTpv2c = (unsigned short*)alloc(2 * 128 * 128 * 2);
  unsigned short* WTnv2c = (unsigned short*)alloc(2 * 128 * 128 * 2);
  unsigned short* WTpc2v = (unsigned short*)alloc(2 * 128 * 128 * 2);
  unsigned short* WTnc2v = (unsigned short*)alloc(2 * 128 * 128 * 2);
  unsigned short* cuWT = (unsigned short*)alloc(128 * 384 * 2);
  unsigned short* vuWT = (unsigned short*)alloc(128 * 384 * 2);
  if ((size_t)(p - (char*)d_ws) > ws_size) return;

  float* vout = (float*)d_out;
  float* cout = vout + (size_t)4 * V * 128;

  // weight prep (bf16 + transpose)
  int t1 = 2 * 128 * 128, t2 = 384 * 128;
  k_wt<<<(t1 + 255) / 256, 256, 0, stream>>>(Wpv2c, 2, 128, 128, WTpv2c);
  k_wt<<<(t1 + 255) / 256, 256, 0, stream>>>(Wnv2c, 2, 128, 128, WTnv2c);
  k_wt<<<(t1 + 255) / 256, 256, 0, stream>>>(Wpc2v, 2, 128, 128, WTpc2v);
  k_wt<<<(t1 + 255) / 256, 256, 0, stream>>>(Wnc2v, 2, 128, 128, WTnc2v);
  k_wt<<<(t2 + 255) / 256, 256, 0, stream>>>(cuW, 1, 384, 128, cuWT);
  k_wt<<<(t2 + 255) / 256, 256, 0, stream>>>(vuW, 1, 384, 128, vuWT);

  // CSR build
  hipMemsetAsync(hist, 0, (size_t)(2 * C + 2 * V) * 4, stream);
  int eb = (2 * Eh + 255) / 256;
  k_endpoints<<<eb, 256, 0, stream>>>(v_edge, c_edge, p_edge, n_edge, Eh, C, V, pv, pc, nv, nc, hist);
  int BC = (C + 1023) >> 10, BV = (V + 1023) >> 10;
  k_scanA<<<2 * BC + 2 * BV, 256, 0, stream>>>(hist, C, V, off_pc, off_nc, off_pv, off_nv, bsums);
  k_scanB<<<4, 256, 0, stream>>>(C, V, off_pc, off_nc, off_pv, off_nv, bsums);
  k_scanC<<<2 * BC + 2 * BV, 256, 0, stream>>>(C, V, off_pc, off_nc, off_pv, off_nv,
                                               cur_pc, cur_nc, cur_pv, cur_nv, bsums);
  k_fill<<<eb, 256, 0, stream>>>(Eh, C, V, pv, pc, nv, nc, hist,
                                 cur_pc, cur_nc, cur_pv, cur_nv,
                                 sPC, wPC, sNC, wNC, sPV, wPV, sNV, wNV);
  hipMemcpyAsync(vout, v_emb0, (size_t)V * 128 * 4, hipMemcpyDeviceToDevice, stream);
  hipMemcpyAsync(cout, c_emb0, (size_t)C * 128 * 4, hipMemcpyDeviceToDevice, stream);

  int vb = (V + 63) / 64, cb = (C + 63) / 64;
  for (int t = 1; t <= 3; t++) {
    const float* vprev = vout + (size_t)(t - 1) * V * 128;
    const float* cprev = cout + (size_t)(t - 1) * C * 128;
    float* vnext = vout + (size_t)t * V * 128;
    float* cnext = cout + (size_t)t * C * 128;
    k_mlp_pair<<<vb, 256, 0, stream>>>(vprev, V, WTpv2c, Bpv2c, WTnv2c, Bnv2c, M1, M2);
    k_update_mfma<<<cb, 256, 0, stream>>>(cprev, C, M1, M2, off_pc, sPC, wPC, off_nc, sNC, wNC,
                                          cuWT, cuB, cnext);
    k_mlp_pair<<<cb, 256, 0, stream>>>(cprev, C, WTpc2v, Bpc2v, WTnc2v, Bnc2v, M1, M2);
    k_update_mfma<<<vb, 256, 0, stream>>>(vprev, V, M1, M2, off_pv, sPV, wPV, off_nv, sNV, wNV,
                                          vuWT, vuB, vnext);
  }
}